// Round 13
// baseline (671.670 us; speedup 1.0000x reference)
//
#include <hip/hip_runtime.h>

// Problem constants (fixed by setup_inputs)
constexpr int B_  = 8;
constexpr int NI  = 4096;
constexpr int NT  = 512;
constexpr int CD  = 1024;

constexpr int BM   = 64;        // img rows per block
constexpr int BK   = 32;        // K per chunk = one mfma_16x16x32 K-step
constexpr int NCH  = CD / BK;   // 32 chunks
constexpr int MAXC = 512;       // candidate list capacity per block
constexpr float DELTA = 0.02f;  // ~50 sigma of fp16 approx error; mean top-2 gap ~0.28

typedef __attribute__((ext_vector_type(4))) float    f32x4;
typedef __attribute__((ext_vector_type(8))) _Float16 f16x8;

// workspace layout: [inv_norm 16K][sidx 128K][wsB 8M]; variant scratch idx
// lives in the last 128K of wsB (rewritten by prep each call).
constexpr size_t WS_NORM_B = 16384;
constexpr size_t WS_IDX_B  = (size_t)B_ * NI * 4;        // 131072
constexpr size_t WSB_OFF   = WS_NORM_B + WS_IDX_B;
constexpr size_t WSB_BYTES = (size_t)B_ * NT * CD * 2;   // 8 MB fp16 text, chunk+q major
constexpr size_t NEED_FULL = WSB_OFF + WSB_BYTES;

// Kernel 1: inv text norms (reduce bit-identical to R1 — refine replicates R1
// fp32 values whose argmax matched np exactly, proven R3-R12) + fp16 pre-scaled
// text, chunk-major q-major: slab(b,kc) = [q:4][t:512][8 halfs] dense (32 KB).
template<bool PRE>
__global__ __launch_bounds__(256) void prep_text_kernel(const float* __restrict__ text,
                                                        float* __restrict__ inv_norm,
                                                        _Float16* __restrict__ wsB) {
    int row  = blockIdx.x * 4 + (threadIdx.x >> 6);
    int lane = threadIdx.x & 63;
    const float* p = text + (size_t)row * CD;
    float s = 0.f;
#pragma unroll
    for (int it = 0; it < 4; ++it) {
        int k = (lane + it * 64) * 4;
        float4 v = *reinterpret_cast<const float4*>(p + k);
        s = fmaf(v.x, v.x, s); s = fmaf(v.y, v.y, s);
        s = fmaf(v.z, v.z, s); s = fmaf(v.w, v.w, s);
    }
#pragma unroll
    for (int off = 32; off > 0; off >>= 1) s += __shfl_xor(s, off);
    float inv = 1.f / fmaxf(sqrtf(s), 1e-12f);
    if (lane == 0) inv_norm[row] = inv;

    if (PRE) {
        int b = row >> 9, t = row & 511;
        int kc = lane >> 1;
        int q0 = (lane & 1) * 2;
        _Float16* slab = wsB + ((size_t)b * 32 + kc) * 16384;
        const float* src = p + lane * 16;
        f16x8 h0, h1;
#pragma unroll
        for (int j = 0; j < 2; ++j) {
            float4 v = *reinterpret_cast<const float4*>(src + j * 4);
            h0[j * 4 + 0] = (_Float16)(v.x * inv); h0[j * 4 + 1] = (_Float16)(v.y * inv);
            h0[j * 4 + 2] = (_Float16)(v.z * inv); h0[j * 4 + 3] = (_Float16)(v.w * inv);
        }
#pragma unroll
        for (int j = 0; j < 2; ++j) {
            float4 v = *reinterpret_cast<const float4*>(src + 8 + j * 4);
            h1[j * 4 + 0] = (_Float16)(v.x * inv); h1[j * 4 + 1] = (_Float16)(v.y * inv);
            h1[j * 4 + 2] = (_Float16)(v.z * inv); h1[j * 4 + 3] = (_Float16)(v.w * inv);
        }
        *reinterpret_cast<f16x8*>(slab + ((q0    ) * 512 + t) * 8) = h0;
        *reinterpret_cast<f16x8*>(slab + ((q0 + 1) * 512 + t) * 8) = h1;
    }
}

struct SmemM {
    _Float16 sA[2][BM * BK];   // 2 x 4096 B, XOR-swizzled rows
};
struct SmemE {
    float pval[4 * BM];
    int   pidx[4 * BM];
    float sval[BM];
    int   sidx[BM];
    int   rowcnt[BM];
    unsigned long long keys[BM];
    int   cand[MAXC];
    int   cnt;
};
union SmemU { SmemM m; SmemE e; };

__device__ __forceinline__ f16x8 packA(float4 a, float4 b) {
    f16x8 h;
    h[0] = (_Float16)a.x; h[1] = (_Float16)a.y; h[2] = (_Float16)a.z; h[3] = (_Float16)a.w;
    h[4] = (_Float16)b.x; h[5] = (_Float16)b.y; h[6] = (_Float16)b.z; h[7] = (_Float16)b.w;
    return h;
}

// Kernel 2: R12's register-pipelined fp16 MFMA sim-GEMM, templated for
// in-round ablation (m233-style):
//   VAR=0: full kernel (identical to R12; writes real gsidx)
//   VAR=1: NO per-chunk B loads (stale live B regs) — isolates A-path+MFMA+barrier
//   VAR=2: NO A global loads / ds_writes (LDS pre-filled) — isolates B-path+MFMA+barrier
// REP repeats the whole K-pipeline (prologue+loop) to lift variants into the
// profiler's top-5 window: visible iff true cost > ~165/REP µs.
template<int WS, int VAR, int REP>
__global__ __launch_bounds__(256, 2) void gemm_kernel(const float* __restrict__ img,
                                                      const float* __restrict__ text,
                                                      const float* __restrict__ inv_norm,
                                                      const _Float16* __restrict__ wsB,
                                                      int* __restrict__ outIdx) {
    __shared__ SmemU sm;

    const int tid = threadIdx.x;
    const int l   = tid & 63;
    const int w   = tid >> 6;      // wave = 128-text slice (0..3)
    const int q   = l >> 4;        // quarter-wave -> k-slice q*8
    const int ln  = l & 15;

    const int b    = blockIdx.x & 7;
    const int row0 = (blockIdx.x >> 3) * BM;

    const float* imgBase  = img  + ((size_t)b * NI + row0) * CD;
    const float* textBase = text + (size_t)b * NT * CD;
    const _Float16* slab  = wsB + (size_t)b * 32 * 16384;   // halfs

    const int arow = tid >> 2, aseg = tid & 3;
    const float* aSrc = imgBase + (size_t)arow * CD + aseg * 8;
    const int aOff = arow * 64 + ((aseg * 16) ^ (((arow >> 1) & 3) << 4)); // byte

    int boff[8];
#pragma unroll
    for (int nj = 0; nj < 8; ++nj)
        boff[nj] = (q * 512 + w * 128 + nj * 16 + ln) * 8;

    float invn8[8];
    if (!WS) {
#pragma unroll
        for (int nj = 0; nj < 8; ++nj)
            invn8[nj] = inv_norm[b * NT + w * 128 + nj * 16 + ln];
    }

    f32x4 acc[4][8];
#pragma unroll
    for (int mi = 0; mi < 4; ++mi)
#pragma unroll
        for (int nj = 0; nj < 8; ++nj) acc[mi][nj] = (f32x4)0.f;

#define LOADB(DST, KC)                                                        \
    {                                                                         \
        const _Float16* sl = slab + (size_t)(KC) * 16384;                     \
        _Pragma("unroll")                                                     \
        for (int nj = 0; nj < 8; ++nj)                                        \
            DST[nj] = *reinterpret_cast<const f16x8*>(sl + boff[nj]);         \
    }
#define LOADB_F(DST, KC)                                                      \
    {                                                                         \
        _Pragma("unroll")                                                     \
        for (int nj = 0; nj < 8; ++nj) {                                      \
            const float* bp = textBase + (size_t)(w * 128 + nj * 16 + ln) * CD \
                            + (KC) * BK + q * 8;                              \
            float4 v0 = *reinterpret_cast<const float4*>(bp);                 \
            float4 v1 = *reinterpret_cast<const float4*>(bp + 4);             \
            float sj = invn8[nj];                                             \
            f16x8 t;                                                          \
            t[0] = (_Float16)(v0.x * sj); t[1] = (_Float16)(v0.y * sj);       \
            t[2] = (_Float16)(v0.z * sj); t[3] = (_Float16)(v0.w * sj);       \
            t[4] = (_Float16)(v1.x * sj); t[5] = (_Float16)(v1.y * sj);       \
            t[6] = (_Float16)(v1.z * sj); t[7] = (_Float16)(v1.w * sj);       \
            DST[nj] = t;                                                      \
        }                                                                     \
    }
#define COMPUTE(BUF, BCUR)                                                    \
    {                                                                         \
        f16x8 af[4];                                                          \
        _Pragma("unroll")                                                     \
        for (int mi = 0; mi < 4; ++mi) {                                      \
            int row = mi * 16 + ln;                                           \
            af[mi] = *reinterpret_cast<const f16x8*>(                         \
                (const char*)&sm.m.sA[BUF][0] + row * 64 +                    \
                ((q * 16) ^ (((row >> 1) & 3) << 4)));                        \
        }                                                                     \
        _Pragma("unroll")                                                     \
        for (int nj = 0; nj < 8; ++nj)                                        \
            _Pragma("unroll")                                                 \
            for (int mi = 0; mi < 4; ++mi)                                    \
                acc[mi][nj] = __builtin_amdgcn_mfma_f32_16x16x32_f16(         \
                    af[mi], BCUR[nj], acc[mi][nj], 0, 0, 0);                  \
    }
#define BARRIER()                                                             \
    asm volatile("s_waitcnt lgkmcnt(0)" ::: "memory");                        \
    __builtin_amdgcn_sched_barrier(0);                                        \
    __builtin_amdgcn_s_barrier();                                             \
    asm volatile("" ::: "memory");

#define STEP(KC, CUR, BCUR, BNXT)                                             \
    {                                                                         \
        const bool mB = ((KC) + 1 < NCH);                                     \
        const bool mL = ((KC) + 3 < NCH);                                     \
        if (VAR != 1 && mB) { if (WS) { LOADB(BNXT, (KC) + 1) } else { LOADB_F(BNXT, (KC) + 1) } } \
        float4 nA0, nA1;                                                      \
        if (VAR != 2 && mL) {                                                 \
            nA0 = *reinterpret_cast<const float4*>(aSrc + ((KC) + 3) * BK);   \
            nA1 = *reinterpret_cast<const float4*>(aSrc + ((KC) + 3) * BK + 4); \
        }                                                                     \
        COMPUTE(CUR, BCUR)                                                    \
        if (VAR != 2 && mB) {                                                 \
            *reinterpret_cast<f16x8*>((char*)&sm.m.sA[(CUR) ^ 1][0] + aOff) = \
                packA(aN1a, aN1b);                                            \
            aN1a = aN2a; aN1b = aN2b;                                         \
            if (mL) { aN2a = nA0; aN2b = nA1; }                               \
        }                                                                     \
        BARRIER()                                                             \
    }

    f16x8 b0[8], b1[8];
    float4 aN1a, aN1b, aN2a, aN2b;

#pragma unroll 1
    for (int rep = 0; rep < REP; ++rep) {
        // ---- prologue ----
        if (WS) { LOADB(b0, 0) } else { LOADB_F(b0, 0) }
        if (VAR == 1) {              // keep b1 live/sane without per-chunk loads
            if (WS) { LOADB(b1, 1) } else { LOADB_F(b1, 1) }
        }
        if (VAR != 2) {
            float4 a0  = *reinterpret_cast<const float4*>(aSrc);
            float4 a0b = *reinterpret_cast<const float4*>(aSrc + 4);
            aN1a = *reinterpret_cast<const float4*>(aSrc + BK);
            aN1b = *reinterpret_cast<const float4*>(aSrc + BK + 4);
            aN2a = *reinterpret_cast<const float4*>(aSrc + 2 * BK);
            aN2b = *reinterpret_cast<const float4*>(aSrc + 2 * BK + 4);
            *reinterpret_cast<f16x8*>((char*)&sm.m.sA[0][0] + aOff) = packA(a0, a0b);
        } else {
            f16x8 z;
#pragma unroll
            for (int j = 0; j < 8; ++j) z[j] = (_Float16)0.f;
            *reinterpret_cast<f16x8*>((char*)&sm.m.sA[0][0] + aOff) = z;
            *reinterpret_cast<f16x8*>((char*)&sm.m.sA[1][0] + aOff) = z;
        }
        BARRIER()

        // ---- main loop: 16 double-steps ----
#pragma unroll 1
        for (int it = 0; it < NCH / 2; ++it) {
            STEP(it * 2,     0, b0, b1)
            STEP(it * 2 + 1, 1, b1, b0)
        }
    }
#undef LOADB
#undef LOADB_F
#undef COMPUTE
#undef BARRIER
#undef STEP

    __syncthreads();   // safe transition to epilogue union

    // --- approx argmax per row WITH index (first-occurrence tie rule) ---
    // C/D layout: col = ln (text), row = q*4 + r  [m89]
#pragma unroll
    for (int mi = 0; mi < 4; ++mi) {
#pragma unroll
        for (int r = 0; r < 4; ++r) {
            float m  = acc[mi][0][r];
            int   bi = w * 128 + ln;
#pragma unroll
            for (int nj = 1; nj < 8; ++nj) {
                float v = acc[mi][nj][r];
                int  ci = w * 128 + nj * 16 + ln;
                if (v > m) { m = v; bi = ci; }
            }
#pragma unroll
            for (int off = 1; off < 16; off <<= 1) {
                float om = __shfl_xor(m, off);
                int   oi = __shfl_xor(bi, off);
                if (om > m || (om == m && oi < bi)) { m = om; bi = oi; }
            }
            if (ln == 0) {
                int rl = mi * 16 + q * 4 + r;
                sm.e.pval[w * BM + rl] = m;
                sm.e.pidx[w * BM + rl] = bi;
            }
        }
    }
    __syncthreads();

    // merge 4 slices (ascending w = ascending text -> first-occurrence holds)
    if (tid < BM) {
        float bv = sm.e.pval[tid];
        int   bi = sm.e.pidx[tid];
#pragma unroll
        for (int ww = 1; ww < 4; ++ww) {
            float v  = sm.e.pval[ww * BM + tid];
            int   i2 = sm.e.pidx[ww * BM + tid];
            if (v > bv || (v == bv && i2 < bi)) { bv = v; bi = i2; }
        }
        sm.e.sval[tid]   = bv;
        sm.e.sidx[tid]   = bi;    // exact answer if rowcnt==1
        sm.e.rowcnt[tid] = 0;
        sm.e.keys[tid]   = 0ull;
    }
    if (tid == 0) sm.e.cnt = 0;
    __syncthreads();

    // candidate collection: all (row,t) with approx >= rowmax - DELTA
    {
        float thr[4][4];
#pragma unroll
        for (int mi = 0; mi < 4; ++mi)
#pragma unroll
            for (int r = 0; r < 4; ++r)
                thr[mi][r] = sm.e.sval[mi * 16 + q * 4 + r] - DELTA;
#pragma unroll
        for (int mi = 0; mi < 4; ++mi)
#pragma unroll
            for (int nj = 0; nj < 8; ++nj)
#pragma unroll
                for (int r = 0; r < 4; ++r) {
                    if (acc[mi][nj][r] >= thr[mi][r]) {
                        int rl = mi * 16 + q * 4 + r;
                        int t  = w * 128 + nj * 16 + ln;
                        atomicAdd(&sm.e.rowcnt[rl], 1);
                        int slot = atomicAdd(&sm.e.cnt, 1);
                        if (slot < MAXC) sm.e.cand[slot] = (rl << 16) | t;
                    }
                }
    }
    __syncthreads();

    // exact fp32 refine, only rows with >=2 candidates (replicates R1
    // arithmetic exactly -> matches np argmax; proven R3-R12)
    {
        int n = sm.e.cnt < MAXC ? sm.e.cnt : MAXC;
        for (int c = tid; c < n; c += 256) {
            int rt = sm.e.cand[c];
            int rl = rt >> 16;
            int t  = rt & 0xFFFF;
            if (sm.e.rowcnt[rl] < 2) continue;
            const float* ap = imgBase  + (size_t)rl * CD;
            const float* bp = textBase + (size_t)t  * CD;
            float s = inv_norm[b * NT + t];
            float accv = 0.f;
#pragma unroll 2
            for (int k = 0; k < CD; k += 4) {
                float4 av = *reinterpret_cast<const float4*>(ap + k);
                float4 bv = *reinterpret_cast<const float4*>(bp + k);
                accv = fmaf(av.x, bv.x * s, accv);
                accv = fmaf(av.y, bv.y * s, accv);
                accv = fmaf(av.z, bv.z * s, accv);
                accv = fmaf(av.w, bv.w * s, accv);
            }
            unsigned ub = __float_as_uint(accv);
            unsigned su = ub ^ ((unsigned)((int)ub >> 31) | 0x80000000u);
            unsigned long long key =
                ((unsigned long long)su << 32) | (unsigned)(NT - 1 - t);
            atomicMax(&sm.e.keys[rl], key);
        }
    }
    __syncthreads();

    // write per-row winning index (real gsidx for VAR=0; scratch otherwise)
    if (tid < BM) {
        int v = sm.e.sidx[tid];
        if (sm.e.rowcnt[tid] > 1)
            v = NT - 1 - (int)(sm.e.keys[tid] & 0xFFFFFFFFull);
        outIdx[(size_t)b * NI + row0 + tid] = v;
    }
}

// Kernel 3: pure streaming gather. Block = 16 rows; text rows L2/L3-hot,
// 64-KB coalesced float4 writes per block. 2048 blocks.
__global__ __launch_bounds__(256) void gather_kernel(const float* __restrict__ text,
                                                     const int* __restrict__ gsidx,
                                                     float* __restrict__ out) {
    __shared__ int idx[16];
    const int tid  = threadIdx.x;
    const int b    = blockIdx.x & 7;
    const int row0 = (blockIdx.x >> 3) * 16;

    if (tid < 16) idx[tid] = gsidx[(size_t)b * NI + row0 + tid];
    __syncthreads();

    const float* textBase = text + (size_t)b * NT * CD;
    float* outBase = out + ((size_t)b * NI + row0) * CD;
#pragma unroll 1
    for (int rr = 0; rr < 16; rr += 2) {
        const float4* s0 = reinterpret_cast<const float4*>(textBase + (size_t)idx[rr]     * CD);
        const float4* s1 = reinterpret_cast<const float4*>(textBase + (size_t)idx[rr + 1] * CD);
        float4 v0 = s0[tid];
        float4 v1 = s1[tid];
        reinterpret_cast<float4*>(outBase + (size_t)(rr    ) * CD)[tid] = v0;
        reinterpret_cast<float4*>(outBase + (size_t)(rr + 1) * CD)[tid] = v1;
    }
}

extern "C" void kernel_launch(void* const* d_in, const int* in_sizes, int n_in,
                              void* d_out, int out_size, void* d_ws, size_t ws_size,
                              hipStream_t stream) {
    const float* img  = (const float*)d_in[0];   // [8,4096,1024] fp32
    const float* text = (const float*)d_in[1];   // [8,512,1024] fp32
    float* out      = (float*)d_out;             // [8,4096,1024] fp32
    float* inv_norm = (float*)d_ws;
    int*   gsidx    = (int*)((char*)d_ws + WS_NORM_B);
    _Float16* wsB   = (_Float16*)((char*)d_ws + WSB_OFF);
    // variant scratch: last 128 KB of wsB (dead data; prep rewrites each call)
    int* scratchIdx = (int*)((char*)d_ws + WSB_OFF + WSB_BYTES - WS_IDX_B);

    const int gridGemm = NI / BM * B_;   // 512
    if (ws_size >= NEED_FULL) {
        prep_text_kernel<true><<<dim3(B_ * NT / 4), 256, 0, stream>>>(text, inv_norm, wsB);
        // V0: real result (identical to R12's kernel)
        gemm_kernel<1, 0, 1><<<dim3(gridGemm), 256, 0, stream>>>(img, text, inv_norm, wsB, gsidx);
        // V1: no per-chunk B loads (A-path + MFMA + barrier), 6x repeated
        gemm_kernel<1, 1, 6><<<dim3(gridGemm), 256, 0, stream>>>(img, text, inv_norm, wsB, scratchIdx);
        // V2: no A staging (B-path + MFMA + barrier), 6x repeated
        gemm_kernel<1, 2, 6><<<dim3(gridGemm), 256, 0, stream>>>(img, text, inv_norm, wsB, scratchIdx);
    } else {
        prep_text_kernel<false><<<dim3(B_ * NT / 4), 256, 0, stream>>>(text, inv_norm, wsB);
        gemm_kernel<0, 0, 1><<<dim3(gridGemm), 256, 0, stream>>>(img, text, inv_norm, wsB, gsidx);
    }
    gather_kernel<<<dim3(B_ * NI / 16), 256, 0, stream>>>(text, gsidx, out);
}

// Round 14
// 128.529 us; speedup vs baseline: 5.2258x; 5.2258x over previous
//
#include <hip/hip_runtime.h>

// Problem constants (fixed by setup_inputs)
constexpr int B_  = 8;
constexpr int NI  = 4096;
constexpr int NT  = 512;
constexpr int CD  = 1024;

constexpr int BM   = 128;       // img rows per block
constexpr int BK   = 64;        // K per tile (2 mfma k-steps)
constexpr int NKT  = CD / BK;   // 16 K-tiles
constexpr int MAXC = 512;       // candidate list capacity per block
constexpr float DELTA = 0.02f;  // ~50 sigma of fp16 approx error; mean top-2 gap ~0.28

typedef __attribute__((ext_vector_type(4))) float    f32x4;
typedef __attribute__((ext_vector_type(8))) _Float16 f16x8;

// workspace layout: [inv_norm 16K][sidx 128K][wsB 8M]
constexpr size_t WS_NORM_B = 16384;
constexpr size_t WS_IDX_B  = (size_t)B_ * NI * 4;        // 131072
constexpr size_t WSB_OFF   = WS_NORM_B + WS_IDX_B;
constexpr size_t WSB_BYTES = (size_t)B_ * NT * CD * 2;   // 8 MB fp16 text
constexpr size_t NEED_FULL = WSB_OFF + WSB_BYTES;

__device__ __forceinline__ void gl_lds16(const void* g, void* l) {
    __builtin_amdgcn_global_load_lds(
        (const __attribute__((address_space(1))) unsigned int*)g,
        (__attribute__((address_space(3))) unsigned int*)l,
        16, 0, 0);
}

__device__ __forceinline__ f16x8 packA(float4 a, float4 b) {
    f16x8 h;
    h[0] = (_Float16)a.x; h[1] = (_Float16)a.y; h[2] = (_Float16)a.z; h[3] = (_Float16)a.w;
    h[4] = (_Float16)b.x; h[5] = (_Float16)b.y; h[6] = (_Float16)b.z; h[7] = (_Float16)b.w;
    return h;
}

// Kernel 1: inv text norms (reduce bit-identical to R1 — refine replicates R1
// fp32 values whose argmax matched np exactly, proven R3-R13) + fp16
// pre-scaled text in K-tile-major slice layout:
//   slab(b,kt) = [slice 0..7][t 0..511][8 halfs]  (64 KB) — the exact linear
//   LDS image for the gemm's B tile (slice = k_local/8).
template<bool PRE>
__global__ __launch_bounds__(256) void prep_text_kernel(const float* __restrict__ text,
                                                        float* __restrict__ inv_norm,
                                                        _Float16* __restrict__ wsB) {
    int row  = blockIdx.x * 4 + (threadIdx.x >> 6);
    int lane = threadIdx.x & 63;
    const float* p = text + (size_t)row * CD;
    float s = 0.f;
#pragma unroll
    for (int it = 0; it < 4; ++it) {
        int k = (lane + it * 64) * 4;
        float4 v = *reinterpret_cast<const float4*>(p + k);
        s = fmaf(v.x, v.x, s); s = fmaf(v.y, v.y, s);
        s = fmaf(v.z, v.z, s); s = fmaf(v.w, v.w, s);
    }
#pragma unroll
    for (int off = 32; off > 0; off >>= 1) s += __shfl_xor(s, off);
    float inv = 1.f / fmaxf(sqrtf(s), 1e-12f);
    if (lane == 0) inv_norm[row] = inv;

    if (PRE) {
        // lane owns k = lane*16..+15 -> tile kt = lane>>2, slices s0, s0+1
        int b = row >> 9, t = row & 511;
        int kt = lane >> 2;
        int s0 = (lane & 3) * 2;
        _Float16* slab = wsB + ((size_t)b * NKT + kt) * 32768;
        const float* src = p + lane * 16;
        f16x8 h0, h1;
#pragma unroll
        for (int j = 0; j < 2; ++j) {
            float4 v = *reinterpret_cast<const float4*>(src + j * 4);
            h0[j * 4 + 0] = (_Float16)(v.x * inv); h0[j * 4 + 1] = (_Float16)(v.y * inv);
            h0[j * 4 + 2] = (_Float16)(v.z * inv); h0[j * 4 + 3] = (_Float16)(v.w * inv);
        }
#pragma unroll
        for (int j = 0; j < 2; ++j) {
            float4 v = *reinterpret_cast<const float4*>(src + 8 + j * 4);
            h1[j * 4 + 0] = (_Float16)(v.x * inv); h1[j * 4 + 1] = (_Float16)(v.y * inv);
            h1[j * 4 + 2] = (_Float16)(v.z * inv); h1[j * 4 + 3] = (_Float16)(v.w * inv);
        }
        *reinterpret_cast<f16x8*>(slab + ((size_t)(s0    ) * 512 + t) * 8) = h0;
        *reinterpret_cast<f16x8*>(slab + ((size_t)(s0 + 1) * 512 + t) * 8) = h1;
    }
}

struct SmemM {
    _Float16 sA[2][8 * BM * 8];   // 2 x 16 KB : [slice][row][8 halfs]
    _Float16 sB[2][8 * NT * 8];   // 2 x 64 KB : [slice][t][8 halfs]
};
struct SmemE {
    float pval[4 * BM];
    int   pidx[4 * BM];
    float sval[BM];
    int   sidx[BM];
    int   rowcnt[BM];
    unsigned long long keys[BM];
    int   cand[MAXC];
    int   cnt;
};
union SmemU { SmemM m; SmemE e; };   // 163840 B (= full 160 KB LDS)

// Kernel 2: big-tile fp16 MFMA sim-GEMM, 2-phase schedule (T3-minimal):
//   tile = 128 rows x 512 texts x BK=64; 16 tiles; ONE vmcnt(0)+barrier per
//   tile amortized over 64 MFMA/wave. A: fp32 glb->reg early, cvt+ds_write
//   late. B: 8 linear global_load_lds from the pre-imaged wsB slab.
//   All ds_reads 256-B contiguous per 16-lane group (slice-major planes).
// 512 thr = 8 waves (2M x 4N); wave owns 64 rows x 128 texts. grid = 256 =
// 1 block/CU, batch-per-XCD. Writes per-row argmax idx (gather separate).
template<int WS>
__global__ __launch_bounds__(512, 2) void gemm_kernel(const float* __restrict__ img,
                                                      const float* __restrict__ text,
                                                      const float* __restrict__ inv_norm,
                                                      const _Float16* __restrict__ wsB,
                                                      int* __restrict__ gsidx) {
    __shared__ SmemU sm;

    const int tid = threadIdx.x;
    const int l   = tid & 63;
    const int w   = tid >> 6;
    const int wm  = w >> 2;        // 0..1 : 64-row half
    const int wn  = w & 3;         // 0..3 : 128-text slice
    const int q   = l >> 4;
    const int ln  = l & 15;

    const int b    = blockIdx.x & 7;           // batch == XCD (round-robin dispatch)
    const int row0 = (blockIdx.x >> 3) * BM;

    const float* imgBase  = img  + ((size_t)b * NI + row0) * CD;
    const float* textBase = text + (size_t)b * NT * CD;
    const char*  bSrc     = (const char*)(wsB + (size_t)b * NKT * 32768);

    // A staging map: thread -> (row = tid>>2, 16-k seg = tid&3); glb reads are
    // 64-B contiguous per row; ds_writes land in slice planes kseg*2, kseg*2+1.
    const int arow = tid >> 2, kseg = tid & 3;
    const float* aSrc = imgBase + (size_t)arow * CD + kseg * 16;
    const int aWr0 = (kseg * 2) * 2048 + arow * 16;   // byte offset in sA buf
    const int aWr1 = aWr0 + 2048;

    float invT = 0.f;
    if (!WS) invT = inv_norm[b * NT + tid];

    f32x4 acc[4][8];
#pragma unroll
    for (int mi = 0; mi < 4; ++mi)
#pragma unroll
        for (int nj = 0; nj < 8; ++nj) acc[mi][nj] = (f32x4)0.f;

#define COMPUTE(CUR)                                                          \
    {                                                                         \
        const char* aB = (const char*)&sm.m.sA[CUR][0];                       \
        const char* bB = (const char*)&sm.m.sB[CUR][0];                       \
        f16x8 af[4][2];                                                       \
        _Pragma("unroll")                                                     \
        for (int mi = 0; mi < 4; ++mi)                                        \
            _Pragma("unroll")                                                 \
            for (int ks = 0; ks < 2; ++ks)                                    \
                af[mi][ks] = *reinterpret_cast<const f16x8*>(                 \
                    aB + (ks * 4 + q) * 2048 + (wm * 64 + mi * 16 + ln) * 16);\
        _Pragma("unroll")                                                     \
        for (int nj = 0; nj < 8; ++nj) {                                      \
            f16x8 bf0 = *reinterpret_cast<const f16x8*>(                      \
                bB + (q) * 8192 + (wn * 128 + nj * 16 + ln) * 16);            \
            f16x8 bf1 = *reinterpret_cast<const f16x8*>(                      \
                bB + (4 + q) * 8192 + (wn * 128 + nj * 16 + ln) * 16);        \
            _Pragma("unroll")                                                 \
            for (int mi = 0; mi < 4; ++mi) {                                  \
                acc[mi][nj] = __builtin_amdgcn_mfma_f32_16x16x32_f16(         \
                    af[mi][0], bf0, acc[mi][nj], 0, 0, 0);                    \
                acc[mi][nj] = __builtin_amdgcn_mfma_f32_16x16x32_f16(         \
                    af[mi][1], bf1, acc[mi][nj], 0, 0, 0);                    \
            }                                                                 \
        }                                                                     \
    }
#define SYNC()                                                                \
    asm volatile("s_waitcnt vmcnt(0)" ::: "memory");                          \
    asm volatile("s_waitcnt lgkmcnt(0)" ::: "memory");                        \
    __builtin_amdgcn_sched_barrier(0);                                        \
    __builtin_amdgcn_s_barrier();                                             \
    asm volatile("" ::: "memory");

    if (WS) {
        // ---- prologue: stage tile 0 into buf 0 ----
        {
            float4 ar[4];
#pragma unroll
            for (int j = 0; j < 4; ++j)
                ar[j] = *reinterpret_cast<const float4*>(aSrc + j * 4);
#pragma unroll
            for (int i = 0; i < 8; ++i)
                gl_lds16(bSrc + i * 8192 + tid * 16,
                         (char*)&sm.m.sB[0][0] + i * 8192 + tid * 16);
            *reinterpret_cast<f16x8*>((char*)&sm.m.sA[0][0] + aWr0) = packA(ar[0], ar[1]);
            *reinterpret_cast<f16x8*>((char*)&sm.m.sA[0][0] + aWr1) = packA(ar[2], ar[3]);
            SYNC()
        }
        // ---- main loop: one vmcnt(0)+barrier per tile ----
#define TILE(KT, CUR)                                                         \
    {                                                                         \
        const bool more = ((KT) + 1 < NKT);                                   \
        float4 ar[4];                                                         \
        if (more) {                                                           \
            _Pragma("unroll")                                                 \
            for (int j = 0; j < 4; ++j)                                       \
                ar[j] = *reinterpret_cast<const float4*>(                     \
                    aSrc + ((KT) + 1) * BK + j * 4);                          \
            const char* bs = bSrc + (size_t)((KT) + 1) * 65536;               \
            _Pragma("unroll")                                                 \
            for (int i = 0; i < 8; ++i)                                       \
                gl_lds16(bs + i * 8192 + tid * 16,                            \
                         (char*)&sm.m.sB[(CUR) ^ 1][0] + i * 8192 + tid * 16);\
        }                                                                     \
        COMPUTE(CUR)                                                          \
        if (more) {                                                           \
            *reinterpret_cast<f16x8*>((char*)&sm.m.sA[(CUR) ^ 1][0] + aWr0) = \
                packA(ar[0], ar[1]);                                          \
            *reinterpret_cast<f16x8*>((char*)&sm.m.sA[(CUR) ^ 1][0] + aWr1) = \
                packA(ar[2], ar[3]);                                          \
        }                                                                     \
        SYNC()                                                                \
    }
#pragma unroll 1
        for (int it = 0; it < NKT / 2; ++it) {
            TILE(it * 2,     0)
            TILE(it * 2 + 1, 1)
        }
#undef TILE
    } else {
        // ---- fallback: single-buffer full-drain (correctness path) ----
#pragma unroll 1
        for (int kt = 0; kt < NKT; ++kt) {
            __syncthreads();
            const float* bp = textBase + (size_t)tid * CD + kt * BK;
#pragma unroll
            for (int j = 0; j < 8; ++j) {
                float4 v0 = *reinterpret_cast<const float4*>(bp + j * 8);
                float4 v1 = *reinterpret_cast<const float4*>(bp + j * 8 + 4);
                f16x8 h;
                h[0] = (_Float16)(v0.x * invT); h[1] = (_Float16)(v0.y * invT);
                h[2] = (_Float16)(v0.z * invT); h[3] = (_Float16)(v0.w * invT);
                h[4] = (_Float16)(v1.x * invT); h[5] = (_Float16)(v1.y * invT);
                h[6] = (_Float16)(v1.z * invT); h[7] = (_Float16)(v1.w * invT);
                *reinterpret_cast<f16x8*>((char*)&sm.m.sB[0][0] + j * 8192 + tid * 16) = h;
            }
            float4 ar[4];
#pragma unroll
            for (int j = 0; j < 4; ++j)
                ar[j] = *reinterpret_cast<const float4*>(aSrc + kt * BK + j * 4);
            *reinterpret_cast<f16x8*>((char*)&sm.m.sA[0][0] + aWr0) = packA(ar[0], ar[1]);
            *reinterpret_cast<f16x8*>((char*)&sm.m.sA[0][0] + aWr1) = packA(ar[2], ar[3]);
            __syncthreads();
            COMPUTE(0)
        }
    }
#undef COMPUTE
#undef SYNC

    __syncthreads();   // safe transition to epilogue union

    // --- approx argmax per row WITH index (first-occurrence tie rule) ---
    // C/D layout: col = ln (text), row = q*4 + r  [m89]
#pragma unroll
    for (int mi = 0; mi < 4; ++mi) {
#pragma unroll
        for (int r = 0; r < 4; ++r) {
            float m  = acc[mi][0][r];
            int   bi = wn * 128 + ln;
#pragma unroll
            for (int nj = 1; nj < 8; ++nj) {
                float v = acc[mi][nj][r];
                int  ci = wn * 128 + nj * 16 + ln;
                if (v > m) { m = v; bi = ci; }
            }
#pragma unroll
            for (int off = 1; off < 16; off <<= 1) {
                float om = __shfl_xor(m, off);
                int   oi = __shfl_xor(bi, off);
                if (om > m || (om == m && oi < bi)) { m = om; bi = oi; }
            }
            if (ln == 0) {
                int rl = wm * 64 + mi * 16 + q * 4 + r;
                sm.e.pval[wn * BM + rl] = m;
                sm.e.pidx[wn * BM + rl] = bi;
            }
        }
    }
    __syncthreads();

    // merge 4 wn slices (ascending wn = ascending text -> first-occurrence)
    if (tid < BM) {
        float bv = sm.e.pval[tid];
        int   bi = sm.e.pidx[tid];
#pragma unroll
        for (int ww = 1; ww < 4; ++ww) {
            float v  = sm.e.pval[ww * BM + tid];
            int   i2 = sm.e.pidx[ww * BM + tid];
            if (v > bv || (v == bv && i2 < bi)) { bv = v; bi = i2; }
        }
        sm.e.sval[tid]   = bv;
        sm.e.sidx[tid]   = bi;    // exact answer if rowcnt==1
        sm.e.rowcnt[tid] = 0;
        sm.e.keys[tid]   = 0ull;
    }
    if (tid == 0) sm.e.cnt = 0;
    __syncthreads();

    // candidate collection: all (row,t) with approx >= rowmax - DELTA
    {
        float thr[4][4];
#pragma unroll
        for (int mi = 0; mi < 4; ++mi)
#pragma unroll
            for (int r = 0; r < 4; ++r)
                thr[mi][r] = sm.e.sval[wm * 64 + mi * 16 + q * 4 + r] - DELTA;
#pragma unroll
        for (int mi = 0; mi < 4; ++mi)
#pragma unroll
            for (int nj = 0; nj < 8; ++nj)
#pragma unroll
                for (int r = 0; r < 4; ++r) {
                    if (acc[mi][nj][r] >= thr[mi][r]) {
                        int rl = wm * 64 + mi * 16 + q * 4 + r;
                        int t  = wn * 128 + nj * 16 + ln;
                        atomicAdd(&sm.e.rowcnt[rl], 1);
                        int slot = atomicAdd(&sm.e.cnt, 1);
                        if (slot < MAXC) sm.e.cand[slot] = (rl << 16) | t;
                    }
                }
    }
    __syncthreads();

    // exact fp32 refine, only rows with >=2 candidates (replicates R1
    // arithmetic exactly -> matches np argmax; proven R3-R13)
    {
        int n = sm.e.cnt < MAXC ? sm.e.cnt : MAXC;
        for (int c = tid; c < n; c += 512) {
            int rt = sm.e.cand[c];
            int rl = rt >> 16;
            int t  = rt & 0xFFFF;
            if (sm.e.rowcnt[rl] < 2) continue;
            const float* ap = imgBase  + (size_t)rl * CD;
            const float* bp = textBase + (size_t)t  * CD;
            float s = inv_norm[b * NT + t];
            float accv = 0.f;
#pragma unroll 2
            for (int k = 0; k < CD; k += 4) {
                float4 av = *reinterpret_cast<const float4*>(ap + k);
                float4 bv = *reinterpret_cast<const float4*>(bp + k);
                accv = fmaf(av.x, bv.x * s, accv);
                accv = fmaf(av.y, bv.y * s, accv);
                accv = fmaf(av.z, bv.z * s, accv);
                accv = fmaf(av.w, bv.w * s, accv);
            }
            unsigned ub = __float_as_uint(accv);
            unsigned su = ub ^ ((unsigned)((int)ub >> 31) | 0x80000000u);
            unsigned long long key =
                ((unsigned long long)su << 32) | (unsigned)(NT - 1 - t);
            atomicMax(&sm.e.keys[rl], key);
        }
    }
    __syncthreads();

    // write per-row winning index to global (128 ints/block)
    if (tid < BM) {
        int v = sm.e.sidx[tid];
        if (sm.e.rowcnt[tid] > 1)
            v = NT - 1 - (int)(sm.e.keys[tid] & 0xFFFFFFFFull);
        gsidx[(size_t)b * NI + row0 + tid] = v;
    }
}

// Kernel 3: pure streaming gather. Block = 16 rows; text rows L2/L3-hot,
// 64-KB coalesced float4 writes per block. 2048 blocks.
__global__ __launch_bounds__(256) void gather_kernel(const float* __restrict__ text,
                                                     const int* __restrict__ gsidx,
                                                     float* __restrict__ out) {
    __shared__ int idx[16];
    const int tid  = threadIdx.x;
    const int b    = blockIdx.x & 7;
    const int row0 = (blockIdx.x >> 3) * 16;

    if (tid < 16) idx[tid] = gsidx[(size_t)b * NI + row0 + tid];
    __syncthreads();

    const float* textBase = text + (size_t)b * NT * CD;
    float* outBase = out + ((size_t)b * NI + row0) * CD;
#pragma unroll 1
    for (int rr = 0; rr < 16; rr += 2) {
        const float4* s0 = reinterpret_cast<const float4*>(textBase + (size_t)idx[rr]     * CD);
        const float4* s1 = reinterpret_cast<const float4*>(textBase + (size_t)idx[rr + 1] * CD);
        float4 v0 = s0[tid];
        float4 v1 = s1[tid];
        reinterpret_cast<float4*>(outBase + (size_t)(rr    ) * CD)[tid] = v0;
        reinterpret_cast<float4*>(outBase + (size_t)(rr + 1) * CD)[tid] = v1;
    }
}

extern "C" void kernel_launch(void* const* d_in, const int* in_sizes, int n_in,
                              void* d_out, int out_size, void* d_ws, size_t ws_size,
                              hipStream_t stream) {
    const float* img  = (const float*)d_in[0];   // [8,4096,1024] fp32
    const float* text = (const float*)d_in[1];   // [8,512,1024] fp32
    float* out      = (float*)d_out;             // [8,4096,1024] fp32
    float* inv_norm = (float*)d_ws;
    int*   gsidx    = (int*)((char*)d_ws + WS_NORM_B);
    _Float16* wsB   = (_Float16*)((char*)d_ws + WSB_OFF);

    const int gridGemm = NI / BM * B_;   // 256 = 1 block/CU
    if (ws_size >= NEED_FULL) {
        prep_text_kernel<true><<<dim3(B_ * NT / 4), 256, 0, stream>>>(text, inv_norm, wsB);
        gemm_kernel<1><<<dim3(gridGemm), 512, 0, stream>>>(img, text, inv_norm, wsB, gsidx);
    } else {
        prep_text_kernel<false><<<dim3(B_ * NT / 4), 256, 0, stream>>>(text, inv_norm, wsB);
        gemm_kernel<0><<<dim3(gridGemm), 512, 0, stream>>>(img, text, inv_norm, wsB, gsidx);
    }
    gather_kernel<<<dim3(B_ * NI / 16), 256, 0, stream>>>(text, gsidx, out);
}